// Round 2
// baseline (411.406 us; speedup 1.0000x reference)
//
#include <hip/hip_runtime.h>

typedef short bf16x8 __attribute__((ext_vector_type(8)));
typedef float f32x4  __attribute__((ext_vector_type(4)));
typedef unsigned int u32x2 __attribute__((ext_vector_type(2)));

#define HID 128
#define TT 32
#define HWSZ 1024
#define PX 32
#define NTHREADS 1024

__device__ __forceinline__ unsigned short f2bf(float f) {
    union { float f; unsigned int i; } v; v.f = f;
    unsigned int u = v.i;
    return (unsigned short)((u + 0x7fffu + ((u >> 16) & 1u)) >> 16);
}
__device__ __forceinline__ unsigned int cvt_pk_bf16(float lo, float hi) {
    unsigned int r;
    asm("v_cvt_pk_bf16_f32 %0, %1, %2" : "=v"(r) : "v"(lo), "v"(hi));
    return r;
}
__device__ __forceinline__ float frcp(float x) { return __builtin_amdgcn_rcpf(x); }
__device__ __forceinline__ float sigm(float x) { return frcp(1.0f + __expf(-x)); }
__device__ __forceinline__ float ftanh(float x){ return 1.0f - 2.0f * frcp(1.0f + __expf(2.0f * x)); }

// lgkm-only barrier: global loads/stores stay in flight across steps.
#define BAR() asm volatile("s_waitcnt lgkmcnt(0)\n\ts_barrier" ::: "memory")

// K-split wave specialization. 16 waves; waves 0-7 ("B") hold W_h (64 VGPR)
// and do h-MFMA + pointwise + outputs; waves 8-15 ("A") hold W_x, compute
// accpart(t+1) = bias + Wx*x_{t+1} during step t (no h dependency) and stage
// x. Handoff via single-buffered f32 accS; 2 lgkm barriers/step:
//   R(t):  B reads accpart(t)                      [A idle]
//   bar1
//   C(t):  B: h-MFMA from hS[t&1] -> pointwise -> hS[(t+1)&1], y stores
//          A: accpart(t+1) from xS[(t+1)&1] -> accS; xreg(x_{t+2}) -> xS[t&1];
//             issue global loads x_{t+3} -> xreg
//   bar0
// h/x LDS tiles XOR-swizzled (idx ^ ((row&7)<<3) in shorts) -> conflict-free
// b128 frag reads. Both roles <= ~128 VGPR -> 4 waves/SIMD (2A+2B per SIMD).
template <int CIN, bool FINAL, bool IN_LOCAL, bool OUT_LOCAL>
__global__ __launch_bounds__(NTHREADS, 4)
void lstm_layer(const void* __restrict__ in_, const float* __restrict__ W,
                const float* __restrict__ bias, void* __restrict__ y_,
                float* __restrict__ hT, float* __restrict__ cT)
{
    constexpr int XK  = CIN / 32;            // x-part k-iters (A)
    constexpr int HK  = HID / 32;            // h-part k-iters (B) = 4
    constexpr int NIT = (PX * CIN / 4) / 512; // fp32 staging iters per A-thread

    const float* inF          = (const float*)in_;
    const unsigned short* inL = (const unsigned short*)in_;
    float* yF                 = (float*)y_;
    unsigned short* yL        = (unsigned short*)y_;

    __shared__ __align__(16) float          accS[8 * 2 * 4 * 256]; // 64 KB
    __shared__ __align__(16) unsigned short hS[2][PX][HID];        // 16 KB
    __shared__ __align__(16) unsigned short xS[2][PX][CIN];        // 8/16 KB
    __shared__ __align__(16) float          biasS[4 * HID];        // 2 KB

    const int tid  = threadIdx.x;
    const int wave = tid >> 6;
    const int lane = tid & 63;
    const int q    = lane >> 4;
    const int ln   = lane & 15;
    const bool isB = wave < 8;
    const int  wp  = wave & 7;

    const int p0  = blockIdx.x * PX;
    const int b   = p0 >> 10;
    const int hw0 = p0 & 1023;

    const long long locbase = (long long)blockIdx.x * TT * PX * HID;
    const long long inFbase = (long long)b * TT * CIN * HWSZ + hw0;

    // ---- shared prologue: bias -> LDS, zero hS[0], stage x0 (B thr) / x1 (A thr)
    if (tid < HID) *(f32x4*)&biasS[tid * 4] = *(const f32x4*)&bias[tid * 4];
    *(u32x2*)&hS[0][tid >> 5][(tid & 31) * 4] = (u32x2){0u, 0u};
    {
        const int t0   = isB ? 0 : 1;
        const int tid2 = isB ? tid : tid - 512;
        if (IN_LOCAL) {
            bf16x8 v = *(const bf16x8*)(inL + locbase + (long long)t0 * PX * HID + tid2 * 8);
            const int px = tid2 >> 4, c8 = (tid2 & 15) * 8;
            *(bf16x8*)&xS[t0][px][c8 ^ ((px & 7) << 3)] = v;
        } else {
            #pragma unroll
            for (int it = 0; it < NIT; ++it) {
                const int idx = tid2 + it * 512;
                const int px = idx & 31, c0 = (idx >> 5) * 4;
                float a[4];
                #pragma unroll
                for (int j = 0; j < 4; ++j)
                    a[j] = inF[inFbase + (long long)t0 * CIN * HWSZ + (c0 + j) * HWSZ + px];
                u32x2 v;
                v[0] = cvt_pk_bf16(a[0], a[1]); v[1] = cvt_pk_bf16(a[2], a[3]);
                *(u32x2*)&xS[t0][px][c0 ^ ((px & 7) << 3)] = v;
            }
        }
    }
    __syncthreads();

    if (isB) {
        // =================== B: h-part + pointwise + outputs ===================
        bf16x8 AfB[HK][4];
        #pragma unroll
        for (int k = 0; k < HK; ++k)
            #pragma unroll
            for (int g = 0; g < 4; ++g) {
                const float* wptr = W + (g * HID + wp * 16 + ln) * (CIN + HID) + CIN + k * 32 + q * 8;
                bf16x8 v;
                #pragma unroll
                for (int j = 0; j < 8; ++j) v[j] = (short)f2bf(wptr[j]);
                AfB[k][g] = v;
            }
        const int ch0 = wp * 16 + q * 4;
        float cst[2][4];
        #pragma unroll
        for (int mt = 0; mt < 2; ++mt)
            #pragma unroll
            for (int r = 0; r < 4; ++r) cst[mt][r] = 0.0f;
        float* const ybase = yF + ((long long)b * TT * HID + ch0) * HWSZ + hw0;

        BAR();   // matches A's accpart(0) phase
        #pragma unroll 2
        for (int t = 0; t < TT; ++t) {
            // ---- R: pull accpart(t) = bias + Wx*x_t
            f32x4 acc[2][4];
            #pragma unroll
            for (int mt = 0; mt < 2; ++mt)
                #pragma unroll
                for (int g = 0; g < 4; ++g)
                    acc[mt][g] = *(const f32x4*)&accS[(((wp * 2 + mt) * 4 + g) * 64 + lane) * 4];
            BAR();
            // ---- C: h-part MFMA
            const unsigned short (*hR)[HID] = hS[t & 1];
            #pragma unroll
            for (int k = 0; k < HK; ++k) {
                const int ofs = (k * 32 + q * 8) ^ ((ln & 7) << 3);
                const bf16x8 p0v = *(const bf16x8*)&hR[ln][ofs];
                const bf16x8 p1v = *(const bf16x8*)&hR[16 + ln][ofs];
                #pragma unroll
                for (int g = 0; g < 4; ++g) {
                    acc[0][g] = __builtin_amdgcn_mfma_f32_16x16x32_bf16(AfB[k][g], p0v, acc[0][g], 0, 0, 0);
                    acc[1][g] = __builtin_amdgcn_mfma_f32_16x16x32_bf16(AfB[k][g], p1v, acc[1][g], 0, 0, 0);
                }
            }
            // ---- pointwise + h/y emit
            #pragma unroll
            for (int mt = 0; mt < 2; ++mt) {
                const int px = mt * 16 + ln;
                float hr[4];
                #pragma unroll
                for (int r = 0; r < 4; ++r) {
                    const float iv = sigm(acc[mt][0][r]);
                    const float fv = sigm(acc[mt][1][r]);
                    const float ov = sigm(acc[mt][2][r]);
                    const float gv = ftanh(acc[mt][3][r]);
                    const float c  = fv * cst[mt][r] + iv * gv;
                    cst[mt][r] = c;
                    hr[r] = ov * ftanh(c);
                    if (FINAL && t == TT - 1)
                        cT[((long long)(b * HID + ch0 + r)) * HWSZ + hw0 + px] = c;
                }
                u32x2 hv;
                hv[0] = cvt_pk_bf16(hr[0], hr[1]);
                hv[1] = cvt_pk_bf16(hr[2], hr[3]);
                *(u32x2*)&hS[(t + 1) & 1][px][ch0 ^ ((px & 7) << 3)] = hv;
                if (FINAL || !OUT_LOCAL) {
                    float* yp = ybase + (long long)t * (HID * HWSZ) + px;
                    yp[0] = hr[0]; yp[HWSZ] = hr[1];
                    yp[2 * HWSZ] = hr[2]; yp[3 * HWSZ] = hr[3];
                    if (FINAL && t == TT - 1) {
                        float* hp = hT + ((long long)(b * HID + ch0)) * HWSZ + hw0 + px;
                        hp[0] = hr[0]; hp[HWSZ] = hr[1];
                        hp[2 * HWSZ] = hr[2]; hp[3 * HWSZ] = hr[3];
                    }
                } else {
                    *(u32x2*)(yL + locbase + ((long long)t * PX + px) * HID + ch0) = hv;
                }
            }
            BAR();
        }
    } else {
        // =================== A: x-part producer + staging ===================
        bf16x8 AfA[XK][4];
        #pragma unroll
        for (int k = 0; k < XK; ++k)
            #pragma unroll
            for (int g = 0; g < 4; ++g) {
                const float* wptr = W + (g * HID + wp * 16 + ln) * (CIN + HID) + k * 32 + q * 8;
                bf16x8 v;
                #pragma unroll
                for (int j = 0; j < 8; ++j) v[j] = (short)f2bf(wptr[j]);
                AfA[k][g] = v;
            }
        const int tid2 = tid - 512;
        bf16x8 xreg8;
        float pff[NIT][4];

        // ---- prologue part 2: accpart(0) = bias + Wx*x_0 (from xS[0])
        {
            f32x4 acc[2][4];
            #pragma unroll
            for (int g = 0; g < 4; ++g) {
                const f32x4 bf = *(const f32x4*)&biasS[g * HID + wp * 16 + q * 4];
                acc[0][g] = bf; acc[1][g] = bf;
            }
            #pragma unroll
            for (int k = 0; k < XK; ++k) {
                const int ofs = (k * 32 + q * 8) ^ ((ln & 7) << 3);
                const bf16x8 p0v = *(const bf16x8*)&xS[0][ln][ofs];
                const bf16x8 p1v = *(const bf16x8*)&xS[0][16 + ln][ofs];
                #pragma unroll
                for (int g = 0; g < 4; ++g) {
                    acc[0][g] = __builtin_amdgcn_mfma_f32_16x16x32_bf16(AfA[k][g], p0v, acc[0][g], 0, 0, 0);
                    acc[1][g] = __builtin_amdgcn_mfma_f32_16x16x32_bf16(AfA[k][g], p1v, acc[1][g], 0, 0, 0);
                }
            }
            #pragma unroll
            for (int mt = 0; mt < 2; ++mt)
                #pragma unroll
                for (int g = 0; g < 4; ++g)
                    *(f32x4*)&accS[(((wp * 2 + mt) * 4 + g) * 64 + lane) * 4] = acc[mt][g];
        }
        // issue x(2) -> regs
        if (IN_LOCAL) {
            xreg8 = *(const bf16x8*)(inL + locbase + (long long)2 * PX * HID + tid2 * 8);
        } else {
            #pragma unroll
            for (int it = 0; it < NIT; ++it) {
                const int idx = tid2 + it * 512;
                const int px = idx & 31, c0 = (idx >> 5) * 4;
                #pragma unroll
                for (int j = 0; j < 4; ++j)
                    pff[it][j] = inF[inFbase + (long long)2 * CIN * HWSZ + (c0 + j) * HWSZ + px];
            }
        }
        BAR();

        #pragma unroll 2
        for (int t = 0; t < TT; ++t) {
            BAR();  // bar1: B finished reading accpart(t)
            // ---- accpart(t+1) = bias + Wx*x_{t+1}
            f32x4 acc[2][4];
            #pragma unroll
            for (int g = 0; g < 4; ++g) {
                const f32x4 bf = *(const f32x4*)&biasS[g * HID + wp * 16 + q * 4];
                acc[0][g] = bf; acc[1][g] = bf;
            }
            const unsigned short (*xR)[CIN] = xS[(t + 1) & 1];
            #pragma unroll
            for (int k = 0; k < XK; ++k) {
                const int ofs = (k * 32 + q * 8) ^ ((ln & 7) << 3);
                const bf16x8 p0v = *(const bf16x8*)&xR[ln][ofs];
                const bf16x8 p1v = *(const bf16x8*)&xR[16 + ln][ofs];
                #pragma unroll
                for (int g = 0; g < 4; ++g) {
                    acc[0][g] = __builtin_amdgcn_mfma_f32_16x16x32_bf16(AfA[k][g], p0v, acc[0][g], 0, 0, 0);
                    acc[1][g] = __builtin_amdgcn_mfma_f32_16x16x32_bf16(AfA[k][g], p1v, acc[1][g], 0, 0, 0);
                }
            }
            #pragma unroll
            for (int mt = 0; mt < 2; ++mt)
                #pragma unroll
                for (int g = 0; g < 4; ++g)
                    *(f32x4*)&accS[(((wp * 2 + mt) * 4 + g) * 64 + lane) * 4] = acc[mt][g];
            // ---- write staged x(t+2) into xS[t&1]
            if (IN_LOCAL) {
                const int px = tid2 >> 4, c8 = (tid2 & 15) * 8;
                *(bf16x8*)&xS[t & 1][px][c8 ^ ((px & 7) << 3)] = xreg8;
            } else {
                #pragma unroll
                for (int it = 0; it < NIT; ++it) {
                    const int idx = tid2 + it * 512;
                    const int px = idx & 31, c0 = (idx >> 5) * 4;
                    u32x2 v;
                    v[0] = cvt_pk_bf16(pff[it][0], pff[it][1]);
                    v[1] = cvt_pk_bf16(pff[it][2], pff[it][3]);
                    *(u32x2*)&xS[t & 1][px][c0 ^ ((px & 7) << 3)] = v;
                }
            }
            // ---- issue x(t+3) loads (consumed next iteration)
            const int tn = (t + 3 < TT) ? t + 3 : TT - 1;
            if (IN_LOCAL) {
                xreg8 = *(const bf16x8*)(inL + locbase + (long long)tn * PX * HID + tid2 * 8);
            } else {
                #pragma unroll
                for (int it = 0; it < NIT; ++it) {
                    const int idx = tid2 + it * 512;
                    const int px = idx & 31, c0 = (idx >> 5) * 4;
                    #pragma unroll
                    for (int j = 0; j < 4; ++j)
                        pff[it][j] = inF[inFbase + (long long)tn * CIN * HWSZ + (c0 + j) * HWSZ + px];
                }
            }
            BAR();  // bar0: step boundary
        }
    }
}

extern "C" void kernel_launch(void* const* d_in, const int* in_sizes, int n_in,
                              void* d_out, int out_size, void* d_ws, size_t ws_size,
                              hipStream_t stream) {
    const float* x  = (const float*)d_in[0];
    const float* W0 = (const float*)d_in[1];
    const float* b0 = (const float*)d_in[2];
    const float* W1 = (const float*)d_in[3];
    const float* b1 = (const float*)d_in[4];
    float* out = (float*)d_out;

    float* y  = out;                      // [8,32,128,32,32] fp32
    float* hT = out + 33554432;           // [8,128,32,32]
    float* cT = out + 34603008;           // [8,128,32,32]

    dim3 grid(8192 / PX), block(NTHREADS);

    const size_t y0_bytes = (size_t)8 * HWSZ * TT * HID * 2;  // 67 MB block-local bf16
    if (ws_size >= y0_bytes) {
        unsigned short* y0 = (unsigned short*)d_ws;
        lstm_layer<64,  false, false, true ><<<grid, block, 0, stream>>>(x,  W0, b0, y0, nullptr, nullptr);
        lstm_layer<128, true,  true,  false><<<grid, block, 0, stream>>>(y0, W1, b1, y,  hT, cT);
    } else {
        // fallback: y0 fp32 [b][t][c][hw] in-place in the y region (reads are
        // always >= 2 steps ahead of writes within a block; layers separate)
        lstm_layer<64,  false, false, false><<<grid, block, 0, stream>>>(x, W0, b0, y, nullptr, nullptr);
        lstm_layer<128, true,  false, false><<<grid, block, 0, stream>>>(y, W1, b1, y, hT, cT);
    }
}

// Round 3
// 344.595 us; speedup vs baseline: 1.1939x; 1.1939x over previous
//
#include <hip/hip_runtime.h>

typedef short bf16x8 __attribute__((ext_vector_type(8)));
typedef float f32x4  __attribute__((ext_vector_type(4)));
typedef unsigned int u32x2 __attribute__((ext_vector_type(2)));

#define HID 128
#define TT 32
#define HWSZ 1024
#define PX 32
#define NTHREADS 512

__device__ __forceinline__ unsigned short f2bf(float f) {
    union { float f; unsigned int i; } v; v.f = f;
    unsigned int u = v.i;
    return (unsigned short)((u + 0x7fffu + ((u >> 16) & 1u)) >> 16);
}
__device__ __forceinline__ unsigned int cvt_pk_bf16(float lo, float hi) {
    unsigned int r;
    asm("v_cvt_pk_bf16_f32 %0, %1, %2" : "=v"(r) : "v"(lo), "v"(hi));
    return r;
}
__device__ __forceinline__ float frcp(float x) { return __builtin_amdgcn_rcpf(x); }

// lgkm-only barrier: global loads/stores stay in flight across steps.
#define BARRIER() asm volatile("s_waitcnt lgkmcnt(0)\n\ts_barrier" ::: "memory")

// One block = PX=32 pixels for the whole sequence; 8 waves; wave w owns
// hidden channels [16w,16w+16) x 4 gates. A = W rows (regs), B = pixels (LDS),
// D reg-dim = channel -> direct register y/hT/cT stores, packed b64 h-writeback.
//
// Round-3 changes vs the 127us round-1 kernel:
//  * pointwise uses common-denominator algebra: 7 trans/output (5 exp + 2 rcp)
//    instead of 10 — the VALU(trans) phase was the largest pipe load.
//  * anti-convoy wave stagger: waves 0-3 do [hMFMA, PW, xMFMA], waves 4-7 do
//    [xMFMA, hMFMA, PW]. With round-robin wave->SIMD mapping each SIMD hosts
//    one of each -> one wave's MFMA issue fills the other wave's trans phase.
//  * s_setprio(1) around PW+h-write (feeds the barrier; critical path).
// LDS row (per px): [x s0 | x s1 | x s2 | h0 | h1 | pad 8], x triple-buffered.
template <int CIN, bool FINAL, bool IN_LOCAL, bool OUT_LOCAL>
__global__ __launch_bounds__(NTHREADS, 2)
void lstm_layer(const void* __restrict__ in_, const float* __restrict__ W,
                const float* __restrict__ bias, void* __restrict__ y_,
                float* __restrict__ hT, float* __restrict__ cT)
{
    constexpr int XK  = CIN / 32;            // x-part k-iters
    constexpr int HK  = HID / 32;            // h-part k-iters
    constexpr int KITERS = XK + HK;
    constexpr int HB0 = 3 * CIN, HB1 = 3 * CIN + HID;
    constexpr int PITCH = 3 * CIN + 2 * HID + 8;   // shorts/row, 16B-aligned rows
    constexpr int NIT = (PX * CIN / 4) / NTHREADS; // fp32-in iters (1 or 2)

    const float* inF          = (const float*)in_;
    const unsigned short* inL = (const unsigned short*)in_;
    float* yF                 = (float*)y_;
    unsigned short* yL        = (unsigned short*)y_;

    __shared__ __align__(16) unsigned short z[PX][PITCH];

    const int tid  = threadIdx.x;
    const int wave = tid >> 6;
    const int lane = tid & 63;
    const int q    = lane >> 4;
    const int ln   = lane & 15;

    const int p0  = blockIdx.x * PX;
    const int b   = p0 >> 10;
    const int hw0 = p0 & 1023;

    const long long locbase = (long long)blockIdx.x * TT * PX * HID;  // local scratch
    const long long inFbase = (long long)b * TT * CIN * HWSZ + hw0;   // fp32 [c][hw]

    // ---- preload W fragments (A operand): rows = gate tiles
    bf16x8 Af[KITERS][4];
    #pragma unroll
    for (int k = 0; k < KITERS; ++k) {
        #pragma unroll
        for (int g = 0; g < 4; ++g) {
            const float* wp = W + (g * HID + wave * 16 + ln) * (CIN + HID) + k * 32 + q * 8;
            bf16x8 v;
            #pragma unroll
            for (int j = 0; j < 8; ++j) v[j] = (short)f2bf(wp[j]);
            Af[k][g] = v;
        }
    }
    // bias: lane's 4 consecutive channels per gate (folded into acc init)
    f32x4 bs[4];
    #pragma unroll
    for (int g = 0; g < 4; ++g)
        bs[g] = *(const f32x4*)(bias + g * HID + wave * 16 + q * 4);

    const int ch0 = wave * 16 + q * 4;   // lane's first channel
    float* const ybase = yF + ((long long)b * TT * HID + ch0) * HWSZ + hw0;

    // ---- zero h buf0; stage x_0 -> slot0, x_1 -> slot1
    #pragma unroll
    for (int idx = tid; idx < PX * HID; idx += NTHREADS)
        z[idx & (PX - 1)][HB0 + (idx >> 5)] = 0;
    if (IN_LOCAL) {
        bf16x8 v0 = *(const bf16x8*)(inL + locbase + tid * 8);
        bf16x8 v1 = *(const bf16x8*)(inL + locbase + (long long)PX * HID + tid * 8);
        *(bf16x8*)&z[tid >> 4][(tid & 15) * 8] = v0;
        *(bf16x8*)&z[tid >> 4][CIN + (tid & 15) * 8] = v1;
    } else {
        #pragma unroll
        for (int it = 0; it < NIT; ++it) {
            const int idx = tid + it * NTHREADS;
            const int pxs = idx & 31, c0 = (idx >> 5) * 4;
            float a0[4], a1[4];
            #pragma unroll
            for (int j = 0; j < 4; ++j) a0[j] = inF[inFbase + (c0 + j) * HWSZ + pxs];
            #pragma unroll
            for (int j = 0; j < 4; ++j) a1[j] = inF[inFbase + (long long)CIN * HWSZ + (c0 + j) * HWSZ + pxs];
            u32x2 v0, v1;
            v0[0] = cvt_pk_bf16(a0[0], a0[1]); v0[1] = cvt_pk_bf16(a0[2], a0[3]);
            v1[0] = cvt_pk_bf16(a1[0], a1[1]); v1[1] = cvt_pk_bf16(a1[2], a1[3]);
            *(u32x2*)&z[pxs][c0] = v0;
            *(u32x2*)&z[pxs][CIN + c0] = v1;
        }
    }
    __syncthreads();

    float cst[2][4];
    #pragma unroll
    for (int mt = 0; mt < 2; ++mt)
        #pragma unroll
        for (int r = 0; r < 4; ++r) cst[mt][r] = 0.0f;

    f32x4 accA[2][4], accB[2][4];
    // prologue: accA = bias + Wx * x_0 (slot 0)
    #pragma unroll
    for (int g = 0; g < 4; ++g) { accA[0][g] = bs[g]; accA[1][g] = bs[g]; }
    #pragma unroll
    for (int k = 0; k < XK; ++k) {
        const int koff = k * 32;
        const bf16x8 pv0 = *(const bf16x8*)&z[ln][koff + q * 8];
        const bf16x8 pv1 = *(const bf16x8*)&z[16 + ln][koff + q * 8];
        #pragma unroll
        for (int g = 0; g < 4; ++g) {
            accA[0][g] = __builtin_amdgcn_mfma_f32_16x16x32_bf16(Af[k][g], pv0, accA[0][g], 0, 0, 0);
            accA[1][g] = __builtin_amdgcn_mfma_f32_16x16x32_bf16(Af[k][g], pv1, accA[1][g], 0, 0, 0);
        }
    }

// ---- step sub-phases -------------------------------------------------------
#define PREFETCH(T)                                                              \
    bf16x8 pfv; float pff[NIT][4];                                               \
    {                                                                            \
        const int tn2 = ((T) + 2 < TT) ? (T) + 2 : TT - 1;                       \
        if (IN_LOCAL) {                                                          \
            pfv = *(const bf16x8*)(inL + locbase + (long long)tn2 * PX * HID + tid * 8); \
        } else {                                                                 \
            _Pragma("unroll")                                                    \
            for (int it = 0; it < NIT; ++it) {                                   \
                const int idx = tid + it * NTHREADS;                             \
                const int pxs = idx & 31, c0 = (idx >> 5) * 4;                   \
                _Pragma("unroll")                                                \
                for (int j = 0; j < 4; ++j)                                      \
                    pff[it][j] = inF[inFbase + (long long)tn2 * CIN * HWSZ + (c0 + j) * HWSZ + pxs]; \
            }                                                                    \
        }                                                                        \
    }

#define HMFMA(ACCC, PAR)                                                         \
    {                                                                            \
        const int hb_r = (PAR) ? HB1 : HB0;                                      \
        _Pragma("unroll")                                                        \
        for (int k = 0; k < HK; ++k) {                                           \
            const int koff = hb_r + k * 32;                                      \
            const bf16x8 pv0 = *(const bf16x8*)&z[ln][koff + q * 8];             \
            const bf16x8 pv1 = *(const bf16x8*)&z[16 + ln][koff + q * 8];        \
            _Pragma("unroll")                                                    \
            for (int g = 0; g < 4; ++g) {                                        \
                ACCC[0][g] = __builtin_amdgcn_mfma_f32_16x16x32_bf16(Af[XK + k][g], pv0, ACCC[0][g], 0, 0, 0); \
                ACCC[1][g] = __builtin_amdgcn_mfma_f32_16x16x32_bf16(Af[XK + k][g], pv1, ACCC[1][g], 0, 0, 0); \
            }                                                                    \
        }                                                                        \
    }

#define XMFMA(ACCN, T)                                                           \
    {                                                                            \
        const int xs_n = ((T) + 1) % 3;                                          \
        _Pragma("unroll")                                                        \
        for (int g = 0; g < 4; ++g) { ACCN[0][g] = bs[g]; ACCN[1][g] = bs[g]; }  \
        _Pragma("unroll")                                                        \
        for (int k = 0; k < XK; ++k) {                                           \
            const int koff = xs_n * CIN + k * 32;                                \
            const bf16x8 pv0 = *(const bf16x8*)&z[ln][koff + q * 8];             \
            const bf16x8 pv1 = *(const bf16x8*)&z[16 + ln][koff + q * 8];        \
            _Pragma("unroll")                                                    \
            for (int g = 0; g < 4; ++g) {                                        \
                ACCN[0][g] = __builtin_amdgcn_mfma_f32_16x16x32_bf16(Af[k][g], pv0, ACCN[0][g], 0, 0, 0); \
                ACCN[1][g] = __builtin_amdgcn_mfma_f32_16x16x32_bf16(Af[k][g], pv1, ACCN[1][g], 0, 0, 0); \
            }                                                                    \
        }                                                                        \
    }

// pointwise (7 trans/output) + h write + y/cT/hT emit. Critical path -> prio 1.
#define PWB(ACCC, T, PAR)                                                        \
    {                                                                            \
        __builtin_amdgcn_s_setprio(1);                                           \
        const int hb_w = (PAR) ? HB0 : HB1;                                      \
        _Pragma("unroll")                                                        \
        for (int mt = 0; mt < 2; ++mt) {                                         \
            const int px = mt * 16 + ln;                                         \
            float hr[4];                                                         \
            _Pragma("unroll")                                                    \
            for (int r = 0; r < 4; ++r) {                                        \
                const float ei = __expf(-ACCC[mt][0][r]);                        \
                const float ef = __expf(-ACCC[mt][1][r]);                        \
                const float eo = __expf(-ACCC[mt][2][r]);                        \
                const float eg = __expf(-2.0f * ACCC[mt][3][r]);                 \
                const float a1 = 1.0f + ei;                                      \
                const float a2 = 1.0f + eg;                                      \
                const float a3 = 1.0f + ef;                                      \
                const float p12 = a1 * a2;                                       \
                const float num = cst[mt][r] * p12 + (1.0f - eg) * a3;           \
                const float c   = num * frcp(a3 * p12);                          \
                cst[mt][r] = c;                                                  \
                const float ec = __expf(-2.0f * c);                              \
                hr[r] = (1.0f - ec) * frcp((1.0f + eo) * (1.0f + ec));           \
                if (FINAL && (T) == TT - 1)                                      \
                    cT[((long long)(b * HID + ch0 + r)) * HWSZ + hw0 + px] = c;  \
            }                                                                    \
            u32x2 hv;                                                            \
            hv[0] = cvt_pk_bf16(hr[0], hr[1]);                                   \
            hv[1] = cvt_pk_bf16(hr[2], hr[3]);                                   \
            *(u32x2*)&z[px][hb_w + ch0] = hv;                                    \
            if (FINAL || !OUT_LOCAL) {                                           \
                float* yp = ybase + (long long)(T) * (HID * HWSZ) + px;          \
                yp[0] = hr[0]; yp[HWSZ] = hr[1];                                 \
                yp[2 * HWSZ] = hr[2]; yp[3 * HWSZ] = hr[3];                      \
                if (FINAL && (T) == TT - 1) {                                    \
                    float* hp = hT + ((long long)(b * HID + ch0)) * HWSZ + hw0 + px; \
                    hp[0] = hr[0]; hp[HWSZ] = hr[1];                             \
                    hp[2 * HWSZ] = hr[2]; hp[3 * HWSZ] = hr[3];                  \
                }                                                                \
            }                                                                    \
        }                                                                        \
        __builtin_amdgcn_s_setprio(0);                                           \
    }

#define XWRITE(T)                                                                \
    {                                                                            \
        const int xs_w = ((T) + 2) % 3;                                          \
        if (IN_LOCAL) {                                                          \
            *(bf16x8*)&z[tid >> 4][xs_w * CIN + (tid & 15) * 8] = pfv;           \
        } else {                                                                 \
            _Pragma("unroll")                                                    \
            for (int it = 0; it < NIT; ++it) {                                   \
                const int idx = tid + it * NTHREADS;                             \
                const int pxs = idx & 31, c0 = (idx >> 5) * 4;                   \
                u32x2 xv;                                                        \
                xv[0] = cvt_pk_bf16(pff[it][0], pff[it][1]);                     \
                xv[1] = cvt_pk_bf16(pff[it][2], pff[it][3]);                     \
                *(u32x2*)&z[pxs][xs_w * CIN + c0] = xv;                          \
            }                                                                    \
        }                                                                        \
    }

#define YEMIT(T, PAR)                                                            \
    if (!FINAL && OUT_LOCAL) {                                                   \
        const int hb_w = (PAR) ? HB0 : HB1;                                      \
        bf16x8 hv8 = *(const bf16x8*)&z[tid >> 4][hb_w + (tid & 15) * 8];        \
        *(bf16x8*)(yL + locbase + (long long)(T) * PX * HID + tid * 8) = hv8;    \
    }

#define STEP_HFIRST(T, PAR, ACCC, ACCN)                                          \
    { PREFETCH(T) HMFMA(ACCC, PAR) PWB(ACCC, T, PAR) XMFMA(ACCN, T)              \
      XWRITE(T) BARRIER(); YEMIT(T, PAR) }

#define STEP_XFIRST(T, PAR, ACCC, ACCN)                                          \
    { PREFETCH(T) XMFMA(ACCN, T) HMFMA(ACCC, PAR) PWB(ACCC, T, PAR)              \
      XWRITE(T) BARRIER(); YEMIT(T, PAR) }

    // anti-convoy stagger: with round-robin wave->SIMD mapping, SIMD k hosts
    // waves {k, k+4} -> one HFIRST + one XFIRST per SIMD.
    if (((wave >> 2) & 1) == 0) {
        for (int t = 0; t < TT; t += 2) {
            STEP_HFIRST(t,     0, accA, accB)
            STEP_HFIRST(t + 1, 1, accB, accA)
        }
    } else {
        for (int t = 0; t < TT; t += 2) {
            STEP_XFIRST(t,     0, accA, accB)
            STEP_XFIRST(t + 1, 1, accB, accA)
        }
    }
#undef PREFETCH
#undef HMFMA
#undef XMFMA
#undef PWB
#undef XWRITE
#undef YEMIT
#undef STEP_HFIRST
#undef STEP_XFIRST
}

extern "C" void kernel_launch(void* const* d_in, const int* in_sizes, int n_in,
                              void* d_out, int out_size, void* d_ws, size_t ws_size,
                              hipStream_t stream) {
    const float* x  = (const float*)d_in[0];
    const float* W0 = (const float*)d_in[1];
    const float* b0 = (const float*)d_in[2];
    const float* W1 = (const float*)d_in[3];
    const float* b1 = (const float*)d_in[4];
    float* out = (float*)d_out;

    float* y  = out;                      // [8,32,128,32,32] fp32
    float* hT = out + 33554432;           // [8,128,32,32]
    float* cT = out + 34603008;           // [8,128,32,32]

    dim3 grid(8192 / PX), block(NTHREADS);

    const size_t y0_bytes = (size_t)8 * HWSZ * TT * HID * 2;  // 67 MB block-local bf16
    if (ws_size >= y0_bytes) {
        unsigned short* y0 = (unsigned short*)d_ws;
        lstm_layer<64,  false, false, true ><<<grid, block, 0, stream>>>(x,  W0, b0, y0, nullptr, nullptr);
        lstm_layer<128, true,  true,  false><<<grid, block, 0, stream>>>(y0, W1, b1, y,  hT, cT);
    } else {
        // fallback: y0 fp32 [b][t][c][hw] in-place in the y region (reads are
        // always >= 2 steps ahead of writes within a block; layers separate)
        lstm_layer<64,  false, false, false><<<grid, block, 0, stream>>>(x, W0, b0, y, nullptr, nullptr);
        lstm_layer<128, true,  false, false><<<grid, block, 0, stream>>>(y, W1, b1, y, hT, cT);
    }
}